// Round 11
// baseline (11593.935 us; speedup 1.0000x reference)
//
#include <hip/hip_runtime.h>
#include <stdint.h>

typedef short short8 __attribute__((ext_vector_type(8)));
typedef float f32x4 __attribute__((ext_vector_type(4)));
typedef unsigned short u16;
typedef unsigned long long u64;

#define MFMA16(a, b, c) __builtin_amdgcn_mfma_f32_16x16x32_bf16((a), (b), (c), 0, 0, 0)

#define T_LEN 512
#define BATCH 64
#define EMB_D 512
#define HID 1024
#define VOC 256
#define NWG 128
#define RNN_THREADS 512

// -------- workspace layout (bytes) --------
#define OFF_H0B   1048576u                   // bf16 h0[2][64][1024]
#define OFF_H1B   1310720u                   // bf16 h1[2][64][1024]
#define HB_ZERO_BYTES 524288u
#define OFF_EMB   1573120u                   // bf16 emb_all[512][64][512]
#define OFF_WIH0  (OFF_EMB + 33554432u)
#define OFF_WHH0  (OFF_WIH0 + 3145728u)
#define OFF_WIH1  (OFF_WHH0 + 6291456u)
#define OFF_WHH1  (OFF_WIH1 + 6291456u)
#define OFF_WOUT  (OFF_WHH1 + 6291456u)
#define OFF_H1ALL (OFF_WOUT + 524288u)       // bf16 h1_all[512*64][1024]
#define OFF_SYNC  (OFF_H1ALL + 67108864u)    // 128 flag lines (128B apart)
#define SYNC_BYTES 16640u
#define WS_TOTAL  (OFF_SYNC + SYNC_BYTES)

static __device__ __forceinline__ u16 f2b(float f) {
  uint32_t u = __float_as_uint(f);
  u += 0x7FFFu + ((u >> 16) & 1u);   // round-to-nearest-even
  return (u16)(u >> 16);
}
static __device__ __forceinline__ float sigm(float x) { return 1.0f / (1.0f + __expf(-x)); }

// coherent (L2-bypassing, sc0sc1) 16B load of an h-state B-fragment:
// two relaxed AGENT-scope 8B atomic loads — no wbl2/buffer_inv, vmcnt-tracked.
static __device__ __forceinline__ short8 loadB_coh(const u16* p) {
  union { u64 q[2]; short8 v; } u;
  u.q[0] = __hip_atomic_load((u64*)p,       __ATOMIC_RELAXED, __HIP_MEMORY_SCOPE_AGENT);
  u.q[1] = __hip_atomic_load((u64*)(p + 4), __ATOMIC_RELAXED, __HIP_MEMORY_SCOPE_AGENT);
  return u.v;
}

// -------- f32 -> bf16 convert --------
__global__ void cvt_kernel(const float* __restrict__ src, u16* __restrict__ dst, int n) {
  int i = ((int)blockIdx.x * 256 + (int)threadIdx.x) * 4;
  if (i + 4 <= n) {
    const float4 v = *(const float4*)(src + i);
    ushort4 o;
    o.x = f2b(v.x); o.y = f2b(v.y); o.z = f2b(v.z); o.w = f2b(v.w);
    *(ushort4*)(dst + i) = o;
  }
}

// -------- embedding gather --------
__global__ void emb_kernel(const int* __restrict__ x, const float* __restrict__ embed,
                           u16* __restrict__ emb_all) {
  const int r = (int)blockIdx.x * 4 + ((int)threadIdx.x >> 6);
  const int c = ((int)threadIdx.x & 63) * 8;
  const int t = r >> 6, b = r & 63;
  const int xi = x[b * T_LEN + t];
  const float* s = embed + (size_t)xi * EMB_D + c;
  const float4 v0 = *(const float4*)s;
  const float4 v1 = *(const float4*)(s + 4);
  ushort4 lo, hi;
  lo.x = f2b(v0.x); lo.y = f2b(v0.y); lo.z = f2b(v0.z); lo.w = f2b(v0.w);
  hi.x = f2b(v1.x); hi.y = f2b(v1.y); hi.z = f2b(v1.z); hi.w = f2b(v1.w);
  u16* d = emb_all + (size_t)r * EMB_D + c;
  *(ushort4*)d = lo;
  *(ushort4*)(d + 4) = hi;
}

// -------- persistent RNN: superstep s = layer0(t=s) || layer1(t=s-1) --------
// h-state moves via relaxed AGENT atomics (sc0sc1, L3-direct): no wbl2/inv on
// the barrier, so weights/emb stay L2-warm across all 512 steps.
// Barrier: vmcnt(0) + syncthreads + relaxed flag store + relaxed all-flag poll.
__global__ __launch_bounds__(RNN_THREADS, 1) void rnn_persist_kernel(
    const u16* __restrict__ emb_all,
    const u16* __restrict__ A0i_r, const u16* __restrict__ A0i_z, const u16* __restrict__ A0i_n,
    const u16* __restrict__ A0h_r, const u16* __restrict__ A0h_z, const u16* __restrict__ A0h_n,
    const u16* __restrict__ A1i_r, const u16* __restrict__ A1i_z, const u16* __restrict__ A1i_n,
    const u16* __restrict__ A1h_r, const u16* __restrict__ A1h_z, const u16* __restrict__ A1h_n,
    const float* __restrict__ bih0, const float* __restrict__ bhh0,
    const float* __restrict__ bih1, const float* __restrict__ bhh1,
    u16* __restrict__ h0b, u16* __restrict__ h1b,
    u16* __restrict__ h1all, unsigned* __restrict__ flags)
{
  __shared__ __align__(16) float lds[16384];
  const int tid = (int)threadIdx.x;
  const int wv = tid >> 6;
  const int lane = tid & 63;
  const int lrow = lane & 15;
  const int lk8 = (lane >> 4) << 3;
  const int wgid = (int)blockIdx.x;
  const int layer = wgid >> 6;
  const int ubase = (wgid & 63) << 4;
  const bool iwave = (wv < 4);
  const bool l0i = (layer == 0) && iwave;

  // ---- role-uniform A config (R7-validated: per-gate pointers, in-loop loads) ----
  const u16 *Ar, *Az, *An;
  int ldb, k0;
  if (layer == 0) {
    if (iwave) { Ar = A0i_r; Az = A0i_z; An = A0i_n; ldb = EMB_D; k0 = wv * 128; }
    else       { Ar = A0h_r; Az = A0h_z; An = A0h_n; ldb = HID;   k0 = (wv - 4) * 256; }
  } else {
    if (iwave) { Ar = A1i_r; Az = A1i_z; An = A1i_n; ldb = HID;   k0 = wv * 256; }
    else       { Ar = A1h_r; Az = A1h_z; An = A1h_n; ldb = HID;   k0 = (wv - 4) * 256; }
  }
  const size_t arow = (size_t)(ubase + lrow) * ldb;

  // ---- epilogue constants: thread owns unit-pair (u0,u0+1) x batch eb ----
  const float* bi = layer ? bih1 : bih0;
  const float* bh = layer ? bhh1 : bhh0;
  const int u0 = (tid & 7) * 2;
  const int eb = tid >> 3;                 // 0..63
  const int eug0 = ubase + u0, eug1 = eug0 + 1;
  const float bR0 = bi[eug0] + bh[eug0];
  const float bZ0 = bi[HID + eug0] + bh[HID + eug0];
  const float bNi0 = bi[2 * HID + eug0];
  const float bNh0 = bh[2 * HID + eug0];
  const float bR1 = bi[eug1] + bh[eug1];
  const float bZ1 = bi[HID + eug1] + bh[HID + eug1];
  const float bNi1 = bi[2 * HID + eug1];
  const float bNh1 = bh[2 * HID + eug1];
  const int l_e = ((u0 >> 2) << 4) | (eb & 15);   // same for u0,u0+1 (u0 even)
  const int r0 = u0 & 3, r1 = r0 + 1;
  const int ebt = eb >> 4;
  const int ix0 = l_e ^ (r0 << 3), ix1 = l_e ^ (r1 << 3);
  u16* hb = layer ? h1b : h0b;
  float hp0 = 0.f, hp1 = 0.f;              // master h in registers

  for (int s = 0; s <= T_LEN; ++s) {
    const bool active = (layer == 0) ? (s < T_LEN) : (s >= 1);
    if (active) {
      const int rdA = ((s + 1) & 1) * (BATCH * HID);  // h0(s-1) slot
      const u16* Bp;
      if (layer == 0) Bp = iwave ? (emb_all + (size_t)s * (BATCH * EMB_D)) : (h0b + rdA);
      else            Bp = iwave ? (h0b + rdA) : (h1b + (s & 1) * (BATCH * HID));

      f32x4 acc0[4], acc1[4], accn[4];
#pragma unroll
      for (int bt = 0; bt < 4; ++bt) {
        acc0[bt] = (f32x4){0.f, 0.f, 0.f, 0.f};
        acc1[bt] = (f32x4){0.f, 0.f, 0.f, 0.f};
        accn[bt] = (f32x4){0.f, 0.f, 0.f, 0.f};
      }
      if (l0i) {  // emb source: normal cached loads
#pragma unroll
        for (int ks = 0; ks < 4; ++ks) {
          const int kk = k0 + ks * 32 + lk8;
          const short8 ar = *(const short8*)(Ar + arow + kk);
          const short8 az = *(const short8*)(Az + arow + kk);
          const short8 an = *(const short8*)(An + arow + kk);
#pragma unroll
          for (int bt = 0; bt < 4; ++bt) {
            const short8 bf = *(const short8*)(Bp + (size_t)(bt * 16 + lrow) * EMB_D + kk);
            acc0[bt] = MFMA16(ar, bf, acc0[bt]);
            acc1[bt] = MFMA16(az, bf, acc1[bt]);
            accn[bt] = MFMA16(an, bf, accn[bt]);
          }
        }
      } else {    // h-state source: coherent loads (fresh from L3, no inv needed)
#pragma unroll
        for (int ks = 0; ks < 8; ++ks) {
          const int kk = k0 + ks * 32 + lk8;
          const short8 ar = *(const short8*)(Ar + arow + kk);
          const short8 az = *(const short8*)(Az + arow + kk);
          const short8 an = *(const short8*)(An + arow + kk);
#pragma unroll
          for (int bt = 0; bt < 4; ++bt) {
            const short8 bf = loadB_coh(Bp + (size_t)(bt * 16 + lrow) * HID + kk);
            acc0[bt] = MFMA16(ar, bf, acc0[bt]);
            acc1[bt] = MFMA16(az, bf, acc1[bt]);
            accn[bt] = MFMA16(an, bf, accn[bt]);
          }
        }
      }
      // reduction round 1: i-waves store groups {0,1,2} (XOR-swizzled)
      if (iwave) {
#pragma unroll
        for (int bt = 0; bt < 4; ++bt)
#pragma unroll
          for (int r = 0; r < 4; ++r) {
            const int ix = lane ^ (r << 3);
            lds[(((wv * 4 + 0) * 4 + bt) * 256) + r * 64 + ix] = acc0[bt][r];
            lds[(((wv * 4 + 1) * 4 + bt) * 256) + r * 64 + ix] = acc1[bt][r];
            lds[(((wv * 4 + 2) * 4 + bt) * 256) + r * 64 + ix] = accn[bt][r];
          }
      }
      __syncthreads();
      // reduction round 2: h-waves add groups {0,1}, store group 3
      if (!iwave) {
        const int z = wv - 4;
#pragma unroll
        for (int bt = 0; bt < 4; ++bt)
#pragma unroll
          for (int r = 0; r < 4; ++r) {
            const int ix = lane ^ (r << 3);
            float* p0 = &lds[(((z * 4 + 0) * 4 + bt) * 256) + r * 64 + ix];
            float* p1 = &lds[(((z * 4 + 1) * 4 + bt) * 256) + r * 64 + ix];
            *p0 = *p0 + acc0[bt][r];
            *p1 = *p1 + acc1[bt][r];
            lds[(((z * 4 + 3) * 4 + bt) * 256) + r * 64 + ix] = accn[bt][r];
          }
      }
      __syncthreads();
      // epilogue: unit-pair per thread, packed 4B coherent h-store
      {
        const int wrt = (layer == 0) ? (s & 1) * (BATCH * HID) : ((s + 1) & 1) * (BATCH * HID);
        float sr0 = 0.f, sz0 = 0.f, sni0 = 0.f, snh0 = 0.f;
        float sr1 = 0.f, sz1 = 0.f, sni1 = 0.f, snh1 = 0.f;
#pragma unroll
        for (int z = 0; z < 4; ++z) {
          sr0  += lds[(((z * 4 + 0) * 4 + ebt) * 256) + r0 * 64 + ix0];
          sz0  += lds[(((z * 4 + 1) * 4 + ebt) * 256) + r0 * 64 + ix0];
          sni0 += lds[(((z * 4 + 2) * 4 + ebt) * 256) + r0 * 64 + ix0];
          snh0 += lds[(((z * 4 + 3) * 4 + ebt) * 256) + r0 * 64 + ix0];
          sr1  += lds[(((z * 4 + 0) * 4 + ebt) * 256) + r1 * 64 + ix1];
          sz1  += lds[(((z * 4 + 1) * 4 + ebt) * 256) + r1 * 64 + ix1];
          sni1 += lds[(((z * 4 + 2) * 4 + ebt) * 256) + r1 * 64 + ix1];
          snh1 += lds[(((z * 4 + 3) * 4 + ebt) * 256) + r1 * 64 + ix1];
        }
        const float rg0 = sigm(sr0 + bR0);
        const float zg0 = sigm(sz0 + bZ0);
        const float ng0 = tanhf(sni0 + bNi0 + rg0 * (snh0 + bNh0));
        const float hn0 = (1.0f - zg0) * ng0 + zg0 * hp0;
        const float rg1 = sigm(sr1 + bR1);
        const float zg1 = sigm(sz1 + bZ1);
        const float ng1 = tanhf(sni1 + bNi1 + rg1 * (snh1 + bNh1));
        const float hn1 = (1.0f - zg1) * ng1 + zg1 * hp1;
        hp0 = hn0; hp1 = hn1;
        const unsigned packed = (unsigned)f2b(hn0) | ((unsigned)f2b(hn1) << 16);
        __hip_atomic_store((unsigned*)&hb[wrt + eb * HID + eug0], packed,
                           __ATOMIC_RELAXED, __HIP_MEMORY_SCOPE_AGENT);
        if (layer)
          *(unsigned*)&h1all[((size_t)(s - 1) * BATCH + eb) * HID + eug0] = packed;
      }
    }
    if (s < T_LEN) {  // barrier: drain h-stores to L3, then flag exchange (no wbl2/inv)
      asm volatile("s_waitcnt vmcnt(0)" ::: "memory");
      __syncthreads();
      const unsigned ep = (unsigned)(s + 1);
      if (tid == 0)
        __hip_atomic_store(&flags[wgid * 32], ep, __ATOMIC_RELAXED, __HIP_MEMORY_SCOPE_AGENT);
      if (tid < NWG) {
        while (__hip_atomic_load(&flags[tid * 32], __ATOMIC_RELAXED,
                                 __HIP_MEMORY_SCOPE_AGENT) < ep)
          __builtin_amdgcn_s_sleep(1);
      }
      asm volatile("" ::: "memory");
      __syncthreads();
    }
  }
}

// -------- epilogue logits (R5-verified MFMA path, decode-0) --------
__global__ __launch_bounds__(256, 2) void logits_kernel(
    const u16* __restrict__ h1all, const u16* __restrict__ Woutb,
    const float* __restrict__ bout, float* __restrict__ out)
{
  __shared__ __align__(16) short lds[16 * 4 * 64 * 8];
  const int tid = (int)threadIdx.x;
  const int wv = tid >> 6, lane = tid & 63;
  const int lrow = lane & 15, lk8 = (lane >> 4) << 3;
  const int row0 = (int)blockIdx.x * 64 + wv * 16;
  f32x4 acc[16];
#pragma unroll
  for (int i = 0; i < 16; ++i) acc[i] = (f32x4){0.f, 0.f, 0.f, 0.f};

  for (int kc = 0; kc < HID; kc += 128) {
    __syncthreads();
#pragma unroll
    for (int j = 0; j < 16; ++j) {
      const int slot = tid + j * 256;
      const int ct = slot >> 8, kt = (slot >> 6) & 3, l = slot & 63;
      *(short8*)&lds[slot * 8] =
          *(const short8*)(Woutb + (size_t)(ct * 16 + (l & 15)) * HID + kc + kt * 32 + ((l >> 4) << 3));
    }
    __syncthreads();
#pragma unroll
    for (int kt = 0; kt < 4; ++kt) {
      const short8 af = *(const short8*)(h1all + (size_t)(row0 + lrow) * HID + kc + kt * 32 + lk8);
#pragma unroll
      for (int ct = 0; ct < 16; ++ct) {
        const short8 bf = *(const short8*)&lds[((ct * 4 + kt) * 64 + lane) * 8];
        acc[ct] = MFMA16(af, bf, acc[ct]);
      }
    }
  }
#pragma unroll
  for (int ct = 0; ct < 16; ++ct) {
    const int v = ct * 16 + lrow;
    const float bo = bout[v];
#pragma unroll
    for (int r = 0; r < 4; ++r) {
      const int row = row0 + (lane >> 4) * 4 + r;  // row = t*64 + b
      const int t = row >> 6, b = row & 63;
      out[((size_t)(b * T_LEN + t)) * VOC + v] = acc[ct][r] + bo;
    }
  }
}

extern "C" void kernel_launch(void* const* d_in, const int* in_sizes, int n_in,
                              void* d_out, int out_size, void* d_ws, size_t ws_size,
                              hipStream_t stream) {
  const int*   x     = (const int*)d_in[0];
  const float* embed = (const float*)d_in[1];
  const float* Wih0  = (const float*)d_in[2];
  const float* Whh0  = (const float*)d_in[3];
  const float* bih0  = (const float*)d_in[4];
  const float* bhh0  = (const float*)d_in[5];
  const float* Wih1  = (const float*)d_in[6];
  const float* Whh1  = (const float*)d_in[7];
  const float* bih1  = (const float*)d_in[8];
  const float* bhh1  = (const float*)d_in[9];
  const float* Wout  = (const float*)d_in[10];
  const float* bout  = (const float*)d_in[11];
  float* out = (float*)d_out;
  char* ws = (char*)d_ws;
  if (ws_size < (size_t)WS_TOTAL) return;

  hipMemsetAsync(ws + OFF_H0B, 0, HB_ZERO_BYTES, stream);  // bf16 h double buffers
  hipMemsetAsync(ws + OFF_SYNC, 0, SYNC_BYTES, stream);    // barrier flags
  cvt_kernel<<<1536, 256, 0, stream>>>(Wih0, (u16*)(ws + OFF_WIH0), 3072 * 512);
  cvt_kernel<<<3072, 256, 0, stream>>>(Whh0, (u16*)(ws + OFF_WHH0), 3072 * 1024);
  cvt_kernel<<<3072, 256, 0, stream>>>(Wih1, (u16*)(ws + OFF_WIH1), 3072 * 1024);
  cvt_kernel<<<3072, 256, 0, stream>>>(Whh1, (u16*)(ws + OFF_WHH1), 3072 * 1024);
  cvt_kernel<<<256, 256, 0, stream>>>(Wout, (u16*)(ws + OFF_WOUT), 256 * 1024);
  emb_kernel<<<8192, 256, 0, stream>>>(x, embed, (u16*)(ws + OFF_EMB));

  const u16* wih0b = (const u16*)(ws + OFF_WIH0);
  const u16* whh0b = (const u16*)(ws + OFF_WHH0);
  const u16* wih1b = (const u16*)(ws + OFF_WIH1);
  const u16* whh1b = (const u16*)(ws + OFF_WHH1);

  rnn_persist_kernel<<<NWG, RNN_THREADS, 0, stream>>>(
      (const u16*)(ws + OFF_EMB),
      wih0b, wih0b + 524288, wih0b + 1048576,
      whh0b, whh0b + 1048576, whh0b + 2097152,
      wih1b, wih1b + 1048576, wih1b + 2097152,
      whh1b, whh1b + 1048576, whh1b + 2097152,
      bih0, bhh0, bih1, bhh1,
      (u16*)(ws + OFF_H0B), (u16*)(ws + OFF_H1B),
      (u16*)(ws + OFF_H1ALL), (unsigned*)(ws + OFF_SYNC));

  logits_kernel<<<512, 256, 0, stream>>>((const u16*)(ws + OFF_H1ALL),
                                         (const u16*)(ws + OFF_WOUT), bout, out);
}

// Round 12
// 7837.577 us; speedup vs baseline: 1.4793x; 1.4793x over previous
//
#include <hip/hip_runtime.h>
#include <stdint.h>

typedef short short8 __attribute__((ext_vector_type(8)));
typedef float f32x4 __attribute__((ext_vector_type(4)));
typedef unsigned short u16;

#define MFMA16(a, b, c) __builtin_amdgcn_mfma_f32_16x16x32_bf16((a), (b), (c), 0, 0, 0)

#define T_LEN 512
#define BATCH 64
#define EMB_D 512
#define HID 1024
#define VOC 256
#define NWG 128
#define RNN_THREADS 512
#define RING 128                              // h-ring slots (power of 2)
#define SLOT (BATCH * HID)                    // u16 elems per ring slot (65536)

// -------- workspace layout (bytes) --------
#define OFF_XT    0u                          // int xT[512][64]           (128 KB)
#define OFF_EMBT  131072u                     // bf16 embtab[256][512]     (256 KB)
#define OFF_WIH0  524288u                     // bf16 [3072][512]          (3 MB)
#define OFF_WHH0  3670016u                    // bf16 [3072][1024]         (6 MB)
#define OFF_WIH1  9961472u
#define OFF_WHH1  16252928u
#define OFF_WOUT  22544384u                   // bf16 [256][1024]          (512 KB)
#define OFF_H0R   23068672u                   // bf16 ring[128][64][1024]  (16 MB)
#define OFF_H1R   39845888u                   // bf16 ring[128][64][1024]  (16 MB)
#define OFF_H1ALL 56623104u                   // bf16 h1_all[512*64][1024] (64 MB)
#define OFF_SYNC  123731968u                  // 128 flag lines (128B apart)
#define SYNC_BYTES 16640u
#define WS_TOTAL  (OFF_SYNC + SYNC_BYTES)     // ~118 MB (< R1-proven 125 MB)

static __device__ __forceinline__ u16 f2b(float f) {
  uint32_t u = __float_as_uint(f);
  u += 0x7FFFu + ((u >> 16) & 1u);   // round-to-nearest-even
  return (u16)(u >> 16);
}
static __device__ __forceinline__ float sigm(float x) { return 1.0f / (1.0f + __expf(-x)); }

// -------- f32 -> bf16 convert --------
__global__ void cvt_kernel(const float* __restrict__ src, u16* __restrict__ dst, int n) {
  int i = ((int)blockIdx.x * 256 + (int)threadIdx.x) * 4;
  if (i + 4 <= n) {
    const float4 v = *(const float4*)(src + i);
    ushort4 o;
    o.x = f2b(v.x); o.y = f2b(v.y); o.z = f2b(v.z); o.w = f2b(v.w);
    *(ushort4*)(dst + i) = o;
  }
}

// -------- token transpose: xT[t][b] = x[b][t] --------
__global__ void xt_kernel(const int* __restrict__ x, int* __restrict__ xT) {
  const int t = (int)blockIdx.x, b = (int)threadIdx.x;
  xT[t * BATCH + b] = x[b * T_LEN + t];
}

// -------- persistent RNN: superstep s = layer0(t=s) || layer1(t=s-1) --------
// h-state in 128-slot rings: consumers cold-miss fresh lines (no buffer_inv
// ever -> weights stay L2-resident). Producers write h via relaxed AGENT
// atomics (R11-proven L3-visible). Barrier = vmcnt-drain + flag exchange only.
__global__ __launch_bounds__(RNN_THREADS, 1) void rnn_persist_kernel(
    const int* __restrict__ xT, const u16* __restrict__ embtab,
    const u16* __restrict__ A0i_r, const u16* __restrict__ A0i_z, const u16* __restrict__ A0i_n,
    const u16* __restrict__ A0h_r, const u16* __restrict__ A0h_z, const u16* __restrict__ A0h_n,
    const u16* __restrict__ A1i_r, const u16* __restrict__ A1i_z, const u16* __restrict__ A1i_n,
    const u16* __restrict__ A1h_r, const u16* __restrict__ A1h_z, const u16* __restrict__ A1h_n,
    const float* __restrict__ bih0, const float* __restrict__ bhh0,
    const float* __restrict__ bih1, const float* __restrict__ bhh1,
    u16* __restrict__ h0r, u16* __restrict__ h1r,
    u16* __restrict__ h1all, unsigned* __restrict__ flags)
{
  __shared__ __align__(16) float lds[16384];
  const int tid = (int)threadIdx.x;
  const int wv = tid >> 6;
  const int lane = tid & 63;
  const int lrow = lane & 15;
  const int lk8 = (lane >> 4) << 3;
  const int wgid = (int)blockIdx.x;
  const int layer = wgid >> 6;
  const int ubase = (wgid & 63) << 4;
  const bool iwave = (wv < 4);
  const bool l0i = (layer == 0) && iwave;

  // ---- role-uniform A config (R7-validated per-gate pointers) ----
  const u16 *Ar, *Az, *An;
  int ldb, k0;
  if (layer == 0) {
    if (iwave) { Ar = A0i_r; Az = A0i_z; An = A0i_n; ldb = EMB_D; k0 = wv * 128; }
    else       { Ar = A0h_r; Az = A0h_z; An = A0h_n; ldb = HID;   k0 = (wv - 4) * 256; }
  } else {
    if (iwave) { Ar = A1i_r; Az = A1i_z; An = A1i_n; ldb = HID;   k0 = wv * 256; }
    else       { Ar = A1h_r; Az = A1h_z; An = A1h_n; ldb = HID;   k0 = (wv - 4) * 256; }
  }
  const size_t arow = (size_t)(ubase + lrow) * ldb;

  // ---- epilogue constants: thread owns unit-pair (u0,u0+1) x batch eb ----
  const float* bi = layer ? bih1 : bih0;
  const float* bh = layer ? bhh1 : bhh0;
  const int u0 = (tid & 7) * 2;
  const int eb = tid >> 3;                 // 0..63
  const int eug0 = ubase + u0, eug1 = eug0 + 1;
  const float bR0 = bi[eug0] + bh[eug0];
  const float bZ0 = bi[HID + eug0] + bh[HID + eug0];
  const float bNi0 = bi[2 * HID + eug0];
  const float bNh0 = bh[2 * HID + eug0];
  const float bR1 = bi[eug1] + bh[eug1];
  const float bZ1 = bi[HID + eug1] + bh[HID + eug1];
  const float bNi1 = bi[2 * HID + eug1];
  const float bNh1 = bh[2 * HID + eug1];
  const int l_e = ((u0 >> 2) << 4) | (eb & 15);
  const int r0 = u0 & 3, r1 = r0 + 1;
  const int ebt = eb >> 4;
  const int ix0 = l_e ^ (r0 << 3), ix1 = l_e ^ (r1 << 3);
  float hp0 = 0.f, hp1 = 0.f;              // master h in registers

  for (int s = 0; s <= T_LEN; ++s) {
    const bool active = (layer == 0) ? (s < T_LEN) : (s >= 1);
    if (active) {
      const u16* h0prev = h0r + (size_t)((s - 1) & (RING - 1)) * SLOT;  // h0(s-1)
      const u16* h1prev = h1r + (size_t)((s - 2) & (RING - 1)) * SLOT;  // h1(s-2)

      f32x4 acc0[4], acc1[4], accn[4];
#pragma unroll
      for (int bt = 0; bt < 4; ++bt) {
        acc0[bt] = (f32x4){0.f, 0.f, 0.f, 0.f};
        acc1[bt] = (f32x4){0.f, 0.f, 0.f, 0.f};
        accn[bt] = (f32x4){0.f, 0.f, 0.f, 0.f};
      }
      if (l0i) {  // B = embed rows gathered by token (embtab L2-resident)
        const u16* brow[4];
#pragma unroll
        for (int bt = 0; bt < 4; ++bt) {
          const int tok = xT[s * BATCH + bt * 16 + lrow];
          brow[bt] = embtab + (size_t)tok * EMB_D;
        }
#pragma unroll
        for (int ks = 0; ks < 4; ++ks) {
          const int kk = k0 + ks * 32 + lk8;
          const short8 ar = *(const short8*)(Ar + arow + kk);
          const short8 az = *(const short8*)(Az + arow + kk);
          const short8 an = *(const short8*)(An + arow + kk);
          const short8 b0 = *(const short8*)(brow[0] + kk);
          const short8 b1 = *(const short8*)(brow[1] + kk);
          const short8 b2 = *(const short8*)(brow[2] + kk);
          const short8 b3 = *(const short8*)(brow[3] + kk);
          acc0[0] = MFMA16(ar, b0, acc0[0]); acc1[0] = MFMA16(az, b0, acc1[0]); accn[0] = MFMA16(an, b0, accn[0]);
          acc0[1] = MFMA16(ar, b1, acc0[1]); acc1[1] = MFMA16(az, b1, acc1[1]); accn[1] = MFMA16(an, b1, accn[1]);
          acc0[2] = MFMA16(ar, b2, acc0[2]); acc1[2] = MFMA16(az, b2, acc1[2]); accn[2] = MFMA16(an, b2, accn[2]);
          acc0[3] = MFMA16(ar, b3, acc0[3]); acc1[3] = MFMA16(az, b3, acc1[3]); accn[3] = MFMA16(an, b3, accn[3]);
        }
      } else {    // B = h ring slot (cached cold-miss reads, L2-amortized per XCD)
        const u16* Bp;
        if (layer == 0) Bp = h0prev;
        else            Bp = iwave ? h0prev : h1prev;
#pragma unroll
        for (int ks = 0; ks < 8; ++ks) {
          const int kk = k0 + ks * 32 + lk8;
          const short8 ar = *(const short8*)(Ar + arow + kk);
          const short8 az = *(const short8*)(Az + arow + kk);
          const short8 an = *(const short8*)(An + arow + kk);
#pragma unroll
          for (int bt = 0; bt < 4; ++bt) {
            const short8 bf = *(const short8*)(Bp + (size_t)(bt * 16 + lrow) * HID + kk);
            acc0[bt] = MFMA16(ar, bf, acc0[bt]);
            acc1[bt] = MFMA16(az, bf, acc1[bt]);
            accn[bt] = MFMA16(an, bf, accn[bt]);
          }
        }
      }
      // reduction round 1: i-waves store groups {0,1,2} (XOR-swizzled)
      if (iwave) {
#pragma unroll
        for (int bt = 0; bt < 4; ++bt)
#pragma unroll
          for (int r = 0; r < 4; ++r) {
            const int ix = lane ^ (r << 3);
            lds[(((wv * 4 + 0) * 4 + bt) * 256) + r * 64 + ix] = acc0[bt][r];
            lds[(((wv * 4 + 1) * 4 + bt) * 256) + r * 64 + ix] = acc1[bt][r];
            lds[(((wv * 4 + 2) * 4 + bt) * 256) + r * 64 + ix] = accn[bt][r];
          }
      }
      __syncthreads();
      // reduction round 2: h-waves add groups {0,1}, store group 3
      if (!iwave) {
        const int z = wv - 4;
#pragma unroll
        for (int bt = 0; bt < 4; ++bt)
#pragma unroll
          for (int r = 0; r < 4; ++r) {
            const int ix = lane ^ (r << 3);
            float* p0 = &lds[(((z * 4 + 0) * 4 + bt) * 256) + r * 64 + ix];
            float* p1 = &lds[(((z * 4 + 1) * 4 + bt) * 256) + r * 64 + ix];
            *p0 = *p0 + acc0[bt][r];
            *p1 = *p1 + acc1[bt][r];
            lds[(((z * 4 + 3) * 4 + bt) * 256) + r * 64 + ix] = accn[bt][r];
          }
      }
      __syncthreads();
      // epilogue: gate math (validated), packed 4B relaxed-atomic h-store to ring
      {
        float sr0 = 0.f, sz0 = 0.f, sni0 = 0.f, snh0 = 0.f;
        float sr1 = 0.f, sz1 = 0.f, sni1 = 0.f, snh1 = 0.f;
#pragma unroll
        for (int z = 0; z < 4; ++z) {
          sr0  += lds[(((z * 4 + 0) * 4 + ebt) * 256) + r0 * 64 + ix0];
          sz0  += lds[(((z * 4 + 1) * 4 + ebt) * 256) + r0 * 64 + ix0];
          sni0 += lds[(((z * 4 + 2) * 4 + ebt) * 256) + r0 * 64 + ix0];
          snh0 += lds[(((z * 4 + 3) * 4 + ebt) * 256) + r0 * 64 + ix0];
          sr1  += lds[(((z * 4 + 0) * 4 + ebt) * 256) + r1 * 64 + ix1];
          sz1  += lds[(((z * 4 + 1) * 4 + ebt) * 256) + r1 * 64 + ix1];
          sni1 += lds[(((z * 4 + 2) * 4 + ebt) * 256) + r1 * 64 + ix1];
          snh1 += lds[(((z * 4 + 3) * 4 + ebt) * 256) + r1 * 64 + ix1];
        }
        const float rg0 = sigm(sr0 + bR0);
        const float zg0 = sigm(sz0 + bZ0);
        const float ng0 = tanhf(sni0 + bNi0 + rg0 * (snh0 + bNh0));
        const float hn0 = (1.0f - zg0) * ng0 + zg0 * hp0;
        const float rg1 = sigm(sr1 + bR1);
        const float zg1 = sigm(sz1 + bZ1);
        const float ng1 = tanhf(sni1 + bNi1 + rg1 * (snh1 + bNh1));
        const float hn1 = (1.0f - zg1) * ng1 + zg1 * hp1;
        hp0 = hn0; hp1 = hn1;
        const unsigned packed = (unsigned)f2b(hn0) | ((unsigned)f2b(hn1) << 16);
        u16* wslot = layer ? (h1r + (size_t)((s - 1) & (RING - 1)) * SLOT)
                           : (h0r + (size_t)(s & (RING - 1)) * SLOT);
        __hip_atomic_store((unsigned*)&wslot[eb * HID + eug0], packed,
                           __ATOMIC_RELAXED, __HIP_MEMORY_SCOPE_AGENT);
        if (layer)
          *(unsigned*)&h1all[((size_t)(s - 1) * BATCH + eb) * HID + eug0] = packed;
      }
    }
    if (s < T_LEN) {  // barrier: syncthreads drains vmcnt -> flag exchange (no cache ops)
      __syncthreads();
      const unsigned ep = (unsigned)(s + 1);
      if (tid == 0)
        __hip_atomic_store(&flags[wgid * 32], ep, __ATOMIC_RELAXED, __HIP_MEMORY_SCOPE_AGENT);
      if (tid < NWG) {
        while (__hip_atomic_load(&flags[tid * 32], __ATOMIC_RELAXED,
                                 __HIP_MEMORY_SCOPE_AGENT) < ep)
          __builtin_amdgcn_s_sleep(1);
      }
      __syncthreads();
    }
  }
}

// -------- epilogue logits (R5-verified MFMA path, decode-0) --------
__global__ __launch_bounds__(256, 2) void logits_kernel(
    const u16* __restrict__ h1all, const u16* __restrict__ Woutb,
    const float* __restrict__ bout, float* __restrict__ out)
{
  __shared__ __align__(16) short lds[16 * 4 * 64 * 8];
  const int tid = (int)threadIdx.x;
  const int wv = tid >> 6, lane = tid & 63;
  const int lrow = lane & 15, lk8 = (lane >> 4) << 3;
  const int row0 = (int)blockIdx.x * 64 + wv * 16;
  f32x4 acc[16];
#pragma unroll
  for (int i = 0; i < 16; ++i) acc[i] = (f32x4){0.f, 0.f, 0.f, 0.f};

  for (int kc = 0; kc < HID; kc += 128) {
    __syncthreads();
#pragma unroll
    for (int j = 0; j < 16; ++j) {
      const int slot = tid + j * 256;
      const int ct = slot >> 8, kt = (slot >> 6) & 3, l = slot & 63;
      *(short8*)&lds[slot * 8] =
          *(const short8*)(Woutb + (size_t)(ct * 16 + (l & 15)) * HID + kc + kt * 32 + ((l >> 4) << 3));
    }
    __syncthreads();
#pragma unroll
    for (int kt = 0; kt < 4; ++kt) {
      const short8 af = *(const short8*)(h1all + (size_t)(row0 + lrow) * HID + kc + kt * 32 + lk8);
#pragma unroll
      for (int ct = 0; ct < 16; ++ct) {
        const short8 bf = *(const short8*)&lds[((ct * 4 + kt) * 64 + lane) * 8];
        acc[ct] = MFMA16(af, bf, acc[ct]);
      }
    }
  }
#pragma unroll
  for (int ct = 0; ct < 16; ++ct) {
    const int v = ct * 16 + lrow;
    const float bo = bout[v];
#pragma unroll
    for (int r = 0; r < 4; ++r) {
      const int row = row0 + (lane >> 4) * 4 + r;  // row = t*64 + b
      const int t = row >> 6, b = row & 63;
      out[((size_t)(b * T_LEN + t)) * VOC + v] = acc[ct][r] + bo;
    }
  }
}

extern "C" void kernel_launch(void* const* d_in, const int* in_sizes, int n_in,
                              void* d_out, int out_size, void* d_ws, size_t ws_size,
                              hipStream_t stream) {
  const int*   x     = (const int*)d_in[0];
  const float* embed = (const float*)d_in[1];
  const float* Wih0  = (const float*)d_in[2];
  const float* Whh0  = (const float*)d_in[3];
  const float* bih0  = (const float*)d_in[4];
  const float* bhh0  = (const float*)d_in[5];
  const float* Wih1  = (const float*)d_in[6];
  const float* Whh1  = (const float*)d_in[7];
  const float* bih1  = (const float*)d_in[8];
  const float* bhh1  = (const float*)d_in[9];
  const float* Wout  = (const float*)d_in[10];
  const float* bout  = (const float*)d_in[11];
  float* out = (float*)d_out;
  char* ws = (char*)d_ws;
  if (ws_size < (size_t)WS_TOTAL) return;

  // zero: ring slot 127 of each h-ring (h(-1)=0) + barrier flags
  hipMemsetAsync(ws + OFF_H0R + (size_t)(RING - 1) * SLOT * 2, 0, SLOT * 2, stream);
  hipMemsetAsync(ws + OFF_H1R + (size_t)(RING - 1) * SLOT * 2, 0, SLOT * 2, stream);
  hipMemsetAsync(ws + OFF_SYNC, 0, SYNC_BYTES, stream);
  xt_kernel<<<512, 64, 0, stream>>>(x, (int*)(ws + OFF_XT));
  cvt_kernel<<<128, 256, 0, stream>>>(embed, (u16*)(ws + OFF_EMBT), 256 * 512);
  cvt_kernel<<<1536, 256, 0, stream>>>(Wih0, (u16*)(ws + OFF_WIH0), 3072 * 512);
  cvt_kernel<<<3072, 256, 0, stream>>>(Whh0, (u16*)(ws + OFF_WHH0), 3072 * 1024);
  cvt_kernel<<<3072, 256, 0, stream>>>(Wih1, (u16*)(ws + OFF_WIH1), 3072 * 1024);
  cvt_kernel<<<3072, 256, 0, stream>>>(Whh1, (u16*)(ws + OFF_WHH1), 3072 * 1024);
  cvt_kernel<<<256, 256, 0, stream>>>(Wout, (u16*)(ws + OFF_WOUT), 256 * 1024);

  const u16* wih0b = (const u16*)(ws + OFF_WIH0);
  const u16* whh0b = (const u16*)(ws + OFF_WHH0);
  const u16* wih1b = (const u16*)(ws + OFF_WIH1);
  const u16* whh1b = (const u16*)(ws + OFF_WHH1);

  rnn_persist_kernel<<<NWG, RNN_THREADS, 0, stream>>>(
      (const int*)(ws + OFF_XT), (const u16*)(ws + OFF_EMBT),
      wih0b, wih0b + 524288, wih0b + 1048576,
      whh0b, whh0b + 1048576, whh0b + 2097152,
      wih1b, wih1b + 1048576, wih1b + 2097152,
      whh1b, whh1b + 1048576, whh1b + 2097152,
      bih0, bhh0, bih1, bhh1,
      (u16*)(ws + OFF_H0R), (u16*)(ws + OFF_H1R),
      (u16*)(ws + OFF_H1ALL), (unsigned*)(ws + OFF_SYNC));

  logits_kernel<<<512, 256, 0, stream>>>((const u16*)(ws + OFF_H1ALL),
                                         (const u16*)(ws + OFF_WOUT), bout, out);
}

// Round 13
// 7786.639 us; speedup vs baseline: 1.4890x; 1.0065x over previous
//
#include <hip/hip_runtime.h>
#include <stdint.h>

typedef short short8 __attribute__((ext_vector_type(8)));
typedef float f32x4 __attribute__((ext_vector_type(4)));
typedef unsigned short u16;

#define MFMA16(a, b, c) __builtin_amdgcn_mfma_f32_16x16x32_bf16((a), (b), (c), 0, 0, 0)

#define T_LEN 512
#define BATCH 64
#define EMB_D 512
#define HID 1024
#define VOC 256
#define NWG 128
#define RNN_THREADS 512
#define R0 256                                // h0 ring slots
#define R1 8                                  // h1 ring slots
#define SLOT (BATCH * HID)                    // u16 elems per ring slot (65536)

// -------- workspace layout (bytes) --------
#define OFF_XT    0u                          // int xT[512][64]           (128 KB)
#define OFF_EMBT  131072u                     // bf16 embtab[256][512]     (256 KB)
#define OFF_WIH0  524288u                     // bf16 [3072][512]          (3 MB)
#define OFF_WHH0  3670016u                    // bf16 [3072][1024]         (6 MB)
#define OFF_WIH1  9961472u
#define OFF_WHH1  16252928u
#define OFF_WOUT  22544384u                   // bf16 [256][1024]          (512 KB)
#define OFF_H0R   23068672u                   // bf16 ring[256][64][1024]  (32 MB)
#define OFF_H1R   56623104u                   // bf16 ring[8][64][1024]    (1 MB)
#define OFF_H1ALL 57671680u                   // bf16 h1_all[512*64][1024] (64 MB)
#define OFF_SYNC  124780544u                  // p0[64]+p1[64] flag lines, 128B apart
#define SYNC_BYTES 16640u
#define WS_TOTAL  (OFF_SYNC + SYNC_BYTES)     // ~119 MB (validated budget)

static __device__ __forceinline__ u16 f2b(float f) {
  uint32_t u = __float_as_uint(f);
  u += 0x7FFFu + ((u >> 16) & 1u);   // round-to-nearest-even
  return (u16)(u >> 16);
}
static __device__ __forceinline__ float sigm(float x) { return 1.0f / (1.0f + __expf(-x)); }

// -------- f32 -> bf16 convert --------
__global__ void cvt_kernel(const float* __restrict__ src, u16* __restrict__ dst, int n) {
  int i = ((int)blockIdx.x * 256 + (int)threadIdx.x) * 4;
  if (i + 4 <= n) {
    const float4 v = *(const float4*)(src + i);
    ushort4 o;
    o.x = f2b(v.x); o.y = f2b(v.y); o.z = f2b(v.z); o.w = f2b(v.w);
    *(ushort4*)(dst + i) = o;
  }
}

// -------- token transpose: xT[t][b] = x[b][t] --------
__global__ void xt_kernel(const int* __restrict__ x, int* __restrict__ xT) {
  const int t = (int)blockIdx.x, b = (int)threadIdx.x;
  xT[t * BATCH + b] = x[b * T_LEN + t];
}

// poll: lanes 0-63 wait p0[lane] >= t0; lanes 64-127 wait p1[lane-64] >= t1
static __device__ __forceinline__ void poll_flags(unsigned* p0, unsigned* p1,
                                                  unsigned t0, unsigned t1, int tid) {
  if (tid < 128) {
    unsigned* f = (tid < 64) ? (p0 + (size_t)tid * 32) : (p1 + (size_t)(tid - 64) * 32);
    const unsigned tgt = (tid < 64) ? t0 : t1;
    while (__hip_atomic_load(f, __ATOMIC_RELAXED, __HIP_MEMORY_SCOPE_AGENT) < tgt)
      __builtin_amdgcn_s_sleep(1);
  }
  __syncthreads();
}

// -------- persistent RNN, decoupled chains --------
// Layer-0 WGs (0-63): own h0 chain, 64-WG offset-1 flag sync (p0).
// Layer-1 WGs (64-127): consume h0 one-way, own h1 chain with 2-step slack (p1).
// h-state in rings (R12-validated cached-read + relaxed-atomic-write pattern).
__global__ __launch_bounds__(RNN_THREADS, 1) void rnn_persist_kernel(
    const int* __restrict__ xT, const u16* __restrict__ embtab,
    const u16* __restrict__ A0i_r, const u16* __restrict__ A0i_z, const u16* __restrict__ A0i_n,
    const u16* __restrict__ A0h_r, const u16* __restrict__ A0h_z, const u16* __restrict__ A0h_n,
    const u16* __restrict__ A1i_r, const u16* __restrict__ A1i_z, const u16* __restrict__ A1i_n,
    const u16* __restrict__ A1h_r, const u16* __restrict__ A1h_z, const u16* __restrict__ A1h_n,
    const float* __restrict__ bih0, const float* __restrict__ bhh0,
    const float* __restrict__ bih1, const float* __restrict__ bhh1,
    u16* __restrict__ h0r, u16* __restrict__ h1r,
    u16* __restrict__ h1all, unsigned* __restrict__ sync)
{
  __shared__ __align__(16) float lds[16384];
  const int tid = (int)threadIdx.x;
  const int wv = tid >> 6;
  const int lane = tid & 63;
  const int lrow = lane & 15;
  const int lk8 = (lane >> 4) << 3;
  const int wgid = (int)blockIdx.x;
  const int layer = wgid >> 6;
  const int ubase = (wgid & 63) << 4;
  const bool iwave = (wv < 4);
  const bool l0i = (layer == 0) && iwave;
  unsigned* p0 = sync;
  unsigned* p1 = sync + 64 * 32;

  // ---- role-uniform A config (R7-validated per-gate pointers) ----
  const u16 *Ar, *Az, *An;
  int ldb, k0;
  if (layer == 0) {
    if (iwave) { Ar = A0i_r; Az = A0i_z; An = A0i_n; ldb = EMB_D; k0 = wv * 128; }
    else       { Ar = A0h_r; Az = A0h_z; An = A0h_n; ldb = HID;   k0 = (wv - 4) * 256; }
  } else {
    if (iwave) { Ar = A1i_r; Az = A1i_z; An = A1i_n; ldb = HID;   k0 = wv * 256; }
    else       { Ar = A1h_r; Az = A1h_z; An = A1h_n; ldb = HID;   k0 = (wv - 4) * 256; }
  }
  const size_t arow = (size_t)(ubase + lrow) * ldb;

  // ---- epilogue constants: thread owns unit-pair (u0,u0+1) x batch eb ----
  const float* bi = layer ? bih1 : bih0;
  const float* bh = layer ? bhh1 : bhh0;
  const int u0 = (tid & 7) * 2;
  const int eb = tid >> 3;
  const int eug0 = ubase + u0, eug1 = eug0 + 1;
  const float bR0 = bi[eug0] + bh[eug0];
  const float bZ0 = bi[HID + eug0] + bh[HID + eug0];
  const float bNi0 = bi[2 * HID + eug0];
  const float bNh0 = bh[2 * HID + eug0];
  const float bR1 = bi[eug1] + bh[eug1];
  const float bZ1 = bi[HID + eug1] + bh[HID + eug1];
  const float bNi1 = bi[2 * HID + eug1];
  const float bNh1 = bh[2 * HID + eug1];
  const int l_e = ((u0 >> 2) << 4) | (eb & 15);
  const int r0 = u0 & 3, r1 = r0 + 1;
  const int ebt = eb >> 4;
  const int ix0 = l_e ^ (r0 << 3), ix1 = l_e ^ (r1 << 3);
  float hp0 = 0.f, hp1 = 0.f;

  const int sBeg = (layer == 0) ? 0 : 1;
  const int sEnd = (layer == 0) ? (T_LEN - 1) : T_LEN;

  for (int s = sBeg; s <= sEnd; ++s) {
    // ---- dependency poll ----
    if (layer == 0) {
      const unsigned bp = (s >= 252) ? (unsigned)(s - 250) : 0u;  // h0-ring back-pressure
      poll_flags(p0, p1, (unsigned)s, bp, tid);
    } else {
      poll_flags(p0, p1, (unsigned)s, (unsigned)(s - 1), tid);
    }

    {
      const u16* h0prev = h0r + (size_t)((s - 1) & (R0 - 1)) * SLOT;  // h0(s-1)
      const u16* h1prev = h1r + (size_t)((s - 2) & (R1 - 1)) * SLOT;  // h1(s-2)

      f32x4 acc0[4], acc1[4], accn[4];
#pragma unroll
      for (int bt = 0; bt < 4; ++bt) {
        acc0[bt] = (f32x4){0.f, 0.f, 0.f, 0.f};
        acc1[bt] = (f32x4){0.f, 0.f, 0.f, 0.f};
        accn[bt] = (f32x4){0.f, 0.f, 0.f, 0.f};
      }
      if (l0i) {  // B = embed rows gathered by token (embtab L2-resident)
        const u16* brow[4];
#pragma unroll
        for (int bt = 0; bt < 4; ++bt) {
          const int tok = xT[s * BATCH + bt * 16 + lrow];
          brow[bt] = embtab + (size_t)tok * EMB_D;
        }
#pragma unroll
        for (int ks = 0; ks < 4; ++ks) {
          const int kk = k0 + ks * 32 + lk8;
          const short8 ar = *(const short8*)(Ar + arow + kk);
          const short8 az = *(const short8*)(Az + arow + kk);
          const short8 an = *(const short8*)(An + arow + kk);
          const short8 b0 = *(const short8*)(brow[0] + kk);
          const short8 b1 = *(const short8*)(brow[1] + kk);
          const short8 b2 = *(const short8*)(brow[2] + kk);
          const short8 b3 = *(const short8*)(brow[3] + kk);
          acc0[0] = MFMA16(ar, b0, acc0[0]); acc1[0] = MFMA16(az, b0, acc1[0]); accn[0] = MFMA16(an, b0, accn[0]);
          acc0[1] = MFMA16(ar, b1, acc0[1]); acc1[1] = MFMA16(az, b1, acc1[1]); accn[1] = MFMA16(an, b1, accn[1]);
          acc0[2] = MFMA16(ar, b2, acc0[2]); acc1[2] = MFMA16(az, b2, acc1[2]); accn[2] = MFMA16(an, b2, accn[2]);
          acc0[3] = MFMA16(ar, b3, acc0[3]); acc1[3] = MFMA16(az, b3, acc1[3]); accn[3] = MFMA16(an, b3, accn[3]);
        }
      } else {    // B = h ring slot (cached cold-miss reads, L2-amortized per XCD)
        const u16* Bp;
        if (layer == 0) Bp = h0prev;
        else            Bp = iwave ? h0prev : h1prev;
#pragma unroll
        for (int ks = 0; ks < 8; ++ks) {
          const int kk = k0 + ks * 32 + lk8;
          const short8 ar = *(const short8*)(Ar + arow + kk);
          const short8 az = *(const short8*)(Az + arow + kk);
          const short8 an = *(const short8*)(An + arow + kk);
#pragma unroll
          for (int bt = 0; bt < 4; ++bt) {
            const short8 bf = *(const short8*)(Bp + (size_t)(bt * 16 + lrow) * HID + kk);
            acc0[bt] = MFMA16(ar, bf, acc0[bt]);
            acc1[bt] = MFMA16(az, bf, acc1[bt]);
            accn[bt] = MFMA16(an, bf, accn[bt]);
          }
        }
      }
      // reduction round 1: i-waves store groups {0,1,2} (XOR-swizzled)
      if (iwave) {
#pragma unroll
        for (int bt = 0; bt < 4; ++bt)
#pragma unroll
          for (int r = 0; r < 4; ++r) {
            const int ix = lane ^ (r << 3);
            lds[(((wv * 4 + 0) * 4 + bt) * 256) + r * 64 + ix] = acc0[bt][r];
            lds[(((wv * 4 + 1) * 4 + bt) * 256) + r * 64 + ix] = acc1[bt][r];
            lds[(((wv * 4 + 2) * 4 + bt) * 256) + r * 64 + ix] = accn[bt][r];
          }
      }
      __syncthreads();
      // reduction round 2: h-waves add groups {0,1}, store group 3
      if (!iwave) {
        const int z = wv - 4;
#pragma unroll
        for (int bt = 0; bt < 4; ++bt)
#pragma unroll
          for (int r = 0; r < 4; ++r) {
            const int ix = lane ^ (r << 3);
            float* q0 = &lds[(((z * 4 + 0) * 4 + bt) * 256) + r * 64 + ix];
            float* q1 = &lds[(((z * 4 + 1) * 4 + bt) * 256) + r * 64 + ix];
            *q0 = *q0 + acc0[bt][r];
            *q1 = *q1 + acc1[bt][r];
            lds[(((z * 4 + 3) * 4 + bt) * 256) + r * 64 + ix] = accn[bt][r];
          }
      }
      __syncthreads();
      // epilogue: gate math (validated), packed 4B relaxed-atomic h-store to ring
      {
        float sr0 = 0.f, sz0 = 0.f, sni0 = 0.f, snh0 = 0.f;
        float sr1 = 0.f, sz1 = 0.f, sni1 = 0.f, snh1 = 0.f;
#pragma unroll
        for (int z = 0; z < 4; ++z) {
          sr0  += lds[(((z * 4 + 0) * 4 + ebt) * 256) + r0 * 64 + ix0];
          sz0  += lds[(((z * 4 + 1) * 4 + ebt) * 256) + r0 * 64 + ix0];
          sni0 += lds[(((z * 4 + 2) * 4 + ebt) * 256) + r0 * 64 + ix0];
          snh0 += lds[(((z * 4 + 3) * 4 + ebt) * 256) + r0 * 64 + ix0];
          sr1  += lds[(((z * 4 + 0) * 4 + ebt) * 256) + r1 * 64 + ix1];
          sz1  += lds[(((z * 4 + 1) * 4 + ebt) * 256) + r1 * 64 + ix1];
          sni1 += lds[(((z * 4 + 2) * 4 + ebt) * 256) + r1 * 64 + ix1];
          snh1 += lds[(((z * 4 + 3) * 4 + ebt) * 256) + r1 * 64 + ix1];
        }
        const float rg0 = sigm(sr0 + bR0);
        const float zg0 = sigm(sz0 + bZ0);
        const float ng0 = tanhf(sni0 + bNi0 + rg0 * (snh0 + bNh0));
        const float hn0 = (1.0f - zg0) * ng0 + zg0 * hp0;
        const float rg1 = sigm(sr1 + bR1);
        const float zg1 = sigm(sz1 + bZ1);
        const float ng1 = tanhf(sni1 + bNi1 + rg1 * (snh1 + bNh1));
        const float hn1 = (1.0f - zg1) * ng1 + zg1 * hp1;
        hp0 = hn0; hp1 = hn1;
        const unsigned packed = (unsigned)f2b(hn0) | ((unsigned)f2b(hn1) << 16);
        u16* wslot = layer ? (h1r + (size_t)((s - 1) & (R1 - 1)) * SLOT)
                           : (h0r + (size_t)(s & (R0 - 1)) * SLOT);
        __hip_atomic_store((unsigned*)&wslot[eb * HID + eug0], packed,
                           __ATOMIC_RELAXED, __HIP_MEMORY_SCOPE_AGENT);
        if (layer)
          *(unsigned*)&h1all[((size_t)(s - 1) * BATCH + eb) * HID + eug0] = packed;
      }
    }
    // ---- publish progress: syncthreads drains vmcnt, then relaxed flag store ----
    __syncthreads();
    if (tid == 0) {
      unsigned* f = layer ? (p1 + (size_t)(wgid - 64) * 32) : (p0 + (size_t)wgid * 32);
      __hip_atomic_store(f, (unsigned)(s + (layer ? 0 : 1)), __ATOMIC_RELAXED,
                         __HIP_MEMORY_SCOPE_AGENT);
    }
  }
}

// -------- epilogue logits (R5-verified MFMA path, decode-0) --------
__global__ __launch_bounds__(256, 2) void logits_kernel(
    const u16* __restrict__ h1all, const u16* __restrict__ Woutb,
    const float* __restrict__ bout, float* __restrict__ out)
{
  __shared__ __align__(16) short lds[16 * 4 * 64 * 8];
  const int tid = (int)threadIdx.x;
  const int wv = tid >> 6, lane = tid & 63;
  const int lrow = lane & 15, lk8 = (lane >> 4) << 3;
  const int row0 = (int)blockIdx.x * 64 + wv * 16;
  f32x4 acc[16];
#pragma unroll
  for (int i = 0; i < 16; ++i) acc[i] = (f32x4){0.f, 0.f, 0.f, 0.f};

  for (int kc = 0; kc < HID; kc += 128) {
    __syncthreads();
#pragma unroll
    for (int j = 0; j < 16; ++j) {
      const int slot = tid + j * 256;
      const int ct = slot >> 8, kt = (slot >> 6) & 3, l = slot & 63;
      *(short8*)&lds[slot * 8] =
          *(const short8*)(Woutb + (size_t)(ct * 16 + (l & 15)) * HID + kc + kt * 32 + ((l >> 4) << 3));
    }
    __syncthreads();
#pragma unroll
    for (int kt = 0; kt < 4; ++kt) {
      const short8 af = *(const short8*)(h1all + (size_t)(row0 + lrow) * HID + kc + kt * 32 + lk8);
#pragma unroll
      for (int ct = 0; ct < 16; ++ct) {
        const short8 bf = *(const short8*)&lds[((ct * 4 + kt) * 64 + lane) * 8];
        acc[ct] = MFMA16(af, bf, acc[ct]);
      }
    }
  }
#pragma unroll
  for (int ct = 0; ct < 16; ++ct) {
    const int v = ct * 16 + lrow;
    const float bo = bout[v];
#pragma unroll
    for (int r = 0; r < 4; ++r) {
      const int row = row0 + (lane >> 4) * 4 + r;  // row = t*64 + b
      const int t = row >> 6, b = row & 63;
      out[((size_t)(b * T_LEN + t)) * VOC + v] = acc[ct][r] + bo;
    }
  }
}

extern "C" void kernel_launch(void* const* d_in, const int* in_sizes, int n_in,
                              void* d_out, int out_size, void* d_ws, size_t ws_size,
                              hipStream_t stream) {
  const int*   x     = (const int*)d_in[0];
  const float* embed = (const float*)d_in[1];
  const float* Wih0  = (const float*)d_in[2];
  const float* Whh0  = (const float*)d_in[3];
  const float* bih0  = (const float*)d_in[4];
  const float* bhh0  = (const float*)d_in[5];
  const float* Wih1  = (const float*)d_in[6];
  const float* Whh1  = (const float*)d_in[7];
  const float* bih1  = (const float*)d_in[8];
  const float* bhh1  = (const float*)d_in[9];
  const float* Wout  = (const float*)d_in[10];
  const float* bout  = (const float*)d_in[11];
  float* out = (float*)d_out;
  char* ws = (char*)d_ws;
  if (ws_size < (size_t)WS_TOTAL) return;

  // zero: h0 ring slot 255 (h0(-1)=0), h1 ring slot 7 (h1(-1)=0), flags
  hipMemsetAsync(ws + OFF_H0R + (size_t)(R0 - 1) * SLOT * 2, 0, SLOT * 2, stream);
  hipMemsetAsync(ws + OFF_H1R + (size_t)(R1 - 1) * SLOT * 2, 0, SLOT * 2, stream);
  hipMemsetAsync(ws + OFF_SYNC, 0, SYNC_BYTES, stream);
  xt_kernel<<<512, 64, 0, stream>>>(x, (int*)(ws + OFF_XT));
  cvt_kernel<<<128, 256, 0, stream>>>(embed, (u16*)(ws + OFF_EMBT), 256 * 512);
  cvt_kernel<<<1536, 256, 0, stream>>>(Wih0, (u16*)(ws + OFF_WIH0), 3072 * 512);
  cvt_kernel<<<3072, 256, 0, stream>>>(Whh0, (u16*)(ws + OFF_WHH0), 3072 * 1024);
  cvt_kernel<<<3072, 256, 0, stream>>>(Wih1, (u16*)(ws + OFF_WIH1), 3072 * 1024);
  cvt_kernel<<<3072, 256, 0, stream>>>(Whh1, (u16*)(ws + OFF_WHH1), 3072 * 1024);
  cvt_kernel<<<256, 256, 0, stream>>>(Wout, (u16*)(ws + OFF_WOUT), 256 * 1024);

  const u16* wih0b = (const u16*)(ws + OFF_WIH0);
  const u16* whh0b = (const u16*)(ws + OFF_WHH0);
  const u16* wih1b = (const u16*)(ws + OFF_WIH1);
  const u16* whh1b = (const u16*)(ws + OFF_WHH1);

  rnn_persist_kernel<<<NWG, RNN_THREADS, 0, stream>>>(
      (const int*)(ws + OFF_XT), (const u16*)(ws + OFF_EMBT),
      wih0b, wih0b + 524288, wih0b + 1048576,
      whh0b, whh0b + 1048576, whh0b + 2097152,
      wih1b, wih1b + 1048576, wih1b + 2097152,
      whh1b, whh1b + 1048576, whh1b + 2097152,
      bih0, bhh0, bih1, bhh1,
      (u16*)(ws + OFF_H0R), (u16*)(ws + OFF_H1R),
      (u16*)(ws + OFF_H1ALL), (unsigned*)(ws + OFF_SYNC));

  logits_kernel<<<512, 256, 0, stream>>>((const u16*)(ws + OFF_H1ALL),
                                         (const u16*)(ws + OFF_WOUT), bout, out);
}